// Round 11
// baseline (15392.159 us; speedup 1.0000x reference)
//
#include <hip/hip_runtime.h>
#include <hip/hip_bf16.h>
#include <math.h>

#define DEV static __device__ __forceinline__

DEV float rl(float v, int i){ return __uint_as_float(__builtin_amdgcn_readlane(__float_as_uint(v), i)); }

typedef float f32x16 __attribute__((ext_vector_type(16)));
typedef unsigned long long u64;

// ---- workspace layout (bytes) ----
static constexpr size_t OFF_H     = 0;                    // 8192*1024*4 = 33554432
static constexpr size_t OFF_FEATS = 33554432;             // 8192*5*4    = 163840
static constexpr size_t OFF_BPS   = OFF_FEATS + 163840;   // 8192*5*4 int
static constexpr size_t OFF_FC    = OFF_BPS + 163840;     // 256*5*4
static constexpr size_t OFF_ECH   = OFF_FC + 5120;        // 256*4
static constexpr size_t OFF_EBEST = OFF_ECH + 1024;       // 256
static constexpr size_t OFF_RC    = OFF_EBEST + 256;      // 64 ints (xg row flags), pad 256
static constexpr size_t OFF_HBUF  = OFF_RC + 256;         // 2*1024*8 = 16384
static constexpr size_t OFF_XG    = OFF_HBUF + 16384;     // 2*8192*2048*4
static constexpr size_t XG_BYTES  = 2ull*8192*2048*4;

#define DOT16(X, OFF, W, B0, B1_, B2_, B3_) \
  _Pragma("unroll") for (int i=0;i<16;i+=4){ \
    B0 =fmaf(rl(X,OFF+i+0),W[i+0],B0 ); B1_=fmaf(rl(X,OFF+i+1),W[i+1],B1_); \
    B2_=fmaf(rl(X,OFF+i+2),W[i+2],B2_); B3_=fmaf(rl(X,OFF+i+3),W[i+3],B3_); }

// =====================================================================
// xg tile worker: one 128x128 fp32 GEMM tile of xg[d][t][row] =
// emb . wih^T. Agent-scope u64 stores (write-through to MALL — per-XCD
// L2s aren't cross-coherent; write-back stores would strand dirty lines).
// Joint __syncthreads drains vmcnt(0) before the row-flag bump.
// =====================================================================
DEV void xg_tile(const float* __restrict__ emb, const float* __restrict__ wihf,
                 const float* __restrict__ wihb, float* __restrict__ xg,
                 int* rowcnt, int tm32, int tn32, bool doflag,
                 float (*As)[132], float (*Bs)[132], int tid)
{
  const int tmb = tm32*128, tnb = tn32*128;
  const int ty = tid >> 4, tx = tid & 15;
  float acc[8][8];
  #pragma unroll
  for (int i=0;i<8;i++)
    #pragma unroll
    for (int j=0;j<8;j++) acc[i][j] = 0.f;

  const int m  = tid & 127;
  const int n  = tnb + m;
  const float* wih = (n & 2048) ? wihb : wihf;
  const float* arow = emb + (size_t)(tmb+m)*768;
  const float* brow = wih + (size_t)(n&2047)*768;
  const int kq = (tid >> 7) << 2;

  for (int k0=0; k0<768; k0+=16){
    #pragma unroll
    for (int r=0;r<2;r++){
      const int kk = kq + r*8;
      float4 v = *reinterpret_cast<const float4*>(arow + k0 + kk);
      As[kk+0][m]=v.x; As[kk+1][m]=v.y; As[kk+2][m]=v.z; As[kk+3][m]=v.w;
      float4 u = *reinterpret_cast<const float4*>(brow + k0 + kk);
      Bs[kk+0][m]=u.x; Bs[kk+1][m]=u.y; Bs[kk+2][m]=u.z; Bs[kk+3][m]=u.w;
    }
    __syncthreads();   // joint 512-thread barrier (both sub-blocks aligned)
    #pragma unroll
    for (int kk2=0;kk2<16;kk2++){
      float4 a0 = *reinterpret_cast<const float4*>(&As[kk2][ty*8]);
      float4 a1 = *reinterpret_cast<const float4*>(&As[kk2][ty*8+4]);
      float4 b0 = *reinterpret_cast<const float4*>(&Bs[kk2][tx*8]);
      float4 b1 = *reinterpret_cast<const float4*>(&Bs[kk2][tx*8+4]);
      float af[8] = {a0.x,a0.y,a0.z,a0.w,a1.x,a1.y,a1.z,a1.w};
      float bf[8] = {b0.x,b0.y,b0.z,b0.w,b1.x,b1.y,b1.z,b1.w};
      #pragma unroll
      for (int i=0;i<8;i++)
        #pragma unroll
        for (int j=0;j<8;j++) acc[i][j] = fmaf(af[i], bf[j], acc[i][j]);
    }
    __syncthreads();
  }

  const int dd = tnb >> 11, nb = tnb & 2047;
  float* xgp = xg + (size_t)dd*8192*2048;
  #pragma unroll
  for (int i=0;i<8;i++){
    float* orow = xgp + (size_t)(tmb+ty*8+i)*2048 + nb + tx*8;
    #pragma unroll
    for (int j=0;j<8;j+=2){
      u64 uu = ((u64)__float_as_uint(acc[i][j+1])<<32) | (u64)__float_as_uint(acc[i][j]);
      __hip_atomic_store(reinterpret_cast<u64*>(orow + j), uu,
                         __ATOMIC_RELAXED, __HIP_MEMORY_SCOPE_AGENT);
    }
  }
  __syncthreads();   // implies s_waitcnt vmcnt(0): agent stores acked at MALL
  if (doflag && tid==0)
    __hip_atomic_fetch_add(rowcnt + tm32, 1, __ATOMIC_RELAXED, __HIP_MEMORY_SCOPE_AGENT);
}

DEV void wait_row(const int* rc, int tm){
  while (__hip_atomic_load(rc + tm, __ATOMIC_RELAXED, __HIP_MEMORY_SCOPE_AGENT) < 32)
    __builtin_amdgcn_s_sleep(8);
  __builtin_amdgcn_sched_barrier(0);
  asm volatile("" ::: "memory");
}

// =====================================================================
// fused_k: 256 blocks x 512 threads (1 block/CU, all co-resident).
//  - blocks 0..63: round-5 persistent BiLSTM (proven agent-scope
//    tag-in-data sync; weights residency irrelevant — sync-bound,
//    confirmed 3x). ROUND-11 CHANGE: software-pipelined poll — 4
//    same-address agent loads in flight (LLVM never CSEs atomics;
//    waitcnt pass emits staged vmcnt(3)) -> sampling period drops from
//    ~1 full MALL latency (~900cy) to ~L/4, cutting the detection
//    quantization term (~150-200ns/step expected).
//  - blocks 64..255: 384 xg-GEMM workers, both-ends-first tile order.
// =====================================================================
__global__ __launch_bounds__(512,2) void fused_k(
    const float* __restrict__ emb,
    const float* __restrict__ wihf, const float* __restrict__ wihb,
    const float* __restrict__ whhf, const float* __restrict__ whhb,
    const float* __restrict__ bihf, const float* __restrict__ bhhf,
    const float* __restrict__ bihb, const float* __restrict__ bhhb,
    const float* __restrict__ h0f, const float* __restrict__ c0f,
    const float* __restrict__ h0b, const float* __restrict__ c0b,
    float* __restrict__ xg, float* __restrict__ H,
    u64* __restrict__ hbuf, int* __restrict__ rowcnt)
{
  __shared__ float smemf[8448];   // workers: 2 x (As+Bs); lstm: part[2][8][64]
  const int b = blockIdx.x;

  if (b >= 64){
    // ---------------- xg worker ----------------
    const int tid = threadIdx.x & 255;
    const int sb  = threadIdx.x >> 8;
    float (*As)[132] = (float(*)[132])(smemf + sb*4224);
    float (*Bs)[132] = (float(*)[132])(smemf + sb*4224 + 2112);
    const int wkr = (b - 64)*2 + sb;          // 0..383
    for (int r=0; r<6; r++){                  // fixed trip for barrier alignment
      int j = wkr + r*384;
      const bool real = (j < 2048);
      if (!real) j = 2047;                    // dummy recompute (flag skipped)
      const int p = j >> 5, tn32 = j & 31;
      const int tm32 = (p & 1) ? (63 - (p>>1)) : (p>>1);   // 0,63,1,62,...
      xg_tile(emb, wihf, wihb, xg, rowcnt, tm32, tn32, real, As, Bs, tid);
    }
    return;
  }

  // ---------------- LSTM role (round-5 body) ----------------
  float (*part)[8][64] = (float(*)[8][64])smemf;   // [2][8][64]
  const int d  = b >> 5;
  const int k  = b & 31;
  const int tid = threadIdx.x;
  const int w  = tid >> 6;
  const int l  = tid & 63;

  const float* whh = d ? whhb : whhf;
  const int grow = (l&3)*512 + k*16 + (l>>2);

  const float* pr = whh + (size_t)grow*512 + w*64;
  f32x16 wr0 = *reinterpret_cast<const f32x16*>(pr);
  f32x16 wr1 = *reinterpret_cast<const f32x16*>(pr+16);
  f32x16 wr2 = *reinterpret_cast<const f32x16*>(pr+32);
  f32x16 wr3 = *reinterpret_cast<const f32x16*>(pr+48);

  const float bias = (d?bihb:bihf)[grow] + (d?bhhb:bhhf)[grow];
  const float* xgp = xg + (size_t)d*8192*2048;

  const float* h0 = d ? h0b : h0f;
  float hv = h0[w*64 + l];
  float c  = (d?c0b:c0f)[k*16 + (l>>2)];

  float xq0 = 0.f, xq1 = 0.f;
  if (w==0){
    wait_row(rowcnt, d ? 63 : 0);           // gate the prologue tile
    xq0 = xgp[(size_t)(d?8191:0)*2048 + grow];
    xq1 = xgp[(size_t)(d?8190:1)*2048 + grow];
  }

  for (int s=0; s<8192; s++){
    const int t  = d ? (8191-s) : s;
    const int pb = s & 1;
    float a0=0.f, a1=0.f, a2=0.f, a3=0.f;
    DOT16(hv, 0, wr0, a0,a1,a2,a3)
    DOT16(hv,16, wr1, a0,a1,a2,a3)
    DOT16(hv,32, wr2, a0,a1,a2,a3)
    DOT16(hv,48, wr3, a0,a1,a2,a3)
    part[pb][w][l] = (a0+a1)+(a2+a3);
    __syncthreads();

    if (w==0){
      float r = ((part[pb][0][l]+part[pb][1][l])+(part[pb][2][l]+part[pb][3][l]))
              + ((part[pb][4][l]+part[pb][5][l])+(part[pb][6][l]+part[pb][7][l]))
              + bias + xq0;
      const bool isg = ((l&3)==2);
      float xx = isg ? 2.f*r : r;
      float sg = 1.f/(1.f + expf(-xx));        // sigmoid
      float a  = isg ? fmaf(2.f,sg,-1.f) : sg; // tanh via 2*sig(2x)-1 for g-gate
      const int lb = l & ~3;
      float ig = __shfl(a, lb);
      float fg = __shfl(a, lb+1);
      float gg = __shfl(a, lb+2);
      float og = __shfl(a, lb+3);
      if ((l&3)==0){
        c = fmaf(fg, c, ig*gg);
        float h = og * tanhf(c);
        const int unit = k*16 + (l>>2);
        u64 pk = ((u64)(unsigned)(s+1) << 32) | (u64)__float_as_uint(h);
        __hip_atomic_store(hbuf + (pb<<10) + d*512 + unit, pk,
                           __ATOMIC_RELAXED, __HIP_MEMORY_SCOPE_AGENT);
        H[(size_t)t*1024 + d*512 + unit] = h;
      }
      // depth-2 xg prefetch for t(s+2), gated at 128-row tile boundaries
      xq0 = xq1;
      if (s<8190){
        const int t2 = d ? (8189-s) : (s+2);
        if (d==0 ? ((t2 & 127)==0) : ((t2 & 127)==127)) wait_row(rowcnt, t2>>7);
        xq1 = xgp[(size_t)t2*2048 + grow];
      }
    }

    if (s<8191){
      const u64* hp = hbuf + (pb<<10) + d*512 + w*64 + l;
      const unsigned want = (unsigned)(s+1);
      // pipelined poll: 4 same-address agent loads in flight; check the
      // oldest (vmcnt(3)) while 3 younger samples are still outstanding.
      u64 q0 = __hip_atomic_load(hp, __ATOMIC_RELAXED, __HIP_MEMORY_SCOPE_AGENT);
      u64 q1 = __hip_atomic_load(hp, __ATOMIC_RELAXED, __HIP_MEMORY_SCOPE_AGENT);
      u64 q2 = __hip_atomic_load(hp, __ATOMIC_RELAXED, __HIP_MEMORY_SCOPE_AGENT);
      u64 q3 = __hip_atomic_load(hp, __ATOMIC_RELAXED, __HIP_MEMORY_SCOPE_AGENT);
      while ((unsigned)(q0>>32) < want){
        q0 = q1; q1 = q2; q2 = q3;
        q3 = __hip_atomic_load(hp, __ATOMIC_RELAXED, __HIP_MEMORY_SCOPE_AGENT);
      }
      hv = __uint_as_float((unsigned)q0);
    }
  }
}

// =====================================================================
// Legacy fallback (round-4/5 single-kernel path) — only if ws too small.
// =====================================================================
__global__ __launch_bounds__(512,2) void lstm_legacy(
    const float* __restrict__ emb,
    const float* __restrict__ whhf, const float* __restrict__ whhb,
    const float* __restrict__ wihf, const float* __restrict__ wihb,
    const float* __restrict__ bihf, const float* __restrict__ bhhf,
    const float* __restrict__ bihb, const float* __restrict__ bhhb,
    const float* __restrict__ h0f, const float* __restrict__ c0f,
    const float* __restrict__ h0b, const float* __restrict__ c0b,
    float* __restrict__ H, u64* __restrict__ hbuf)
{
  const int b  = blockIdx.x;
  const int d  = b >> 5;
  const int k  = b & 31;
  const int tid = threadIdx.x;
  const int w  = tid >> 6;
  const int l  = tid & 63;

  const float* whh = d ? whhb : whhf;
  const float* wih = d ? wihb : wihf;
  const int grow = (l&3)*512 + k*16 + (l>>2);

  const float* pr = whh + (size_t)grow*512 + w*64;
  f32x16 wr0 = *reinterpret_cast<const f32x16*>(pr);
  f32x16 wr1 = *reinterpret_cast<const f32x16*>(pr+16);
  f32x16 wr2 = *reinterpret_cast<const f32x16*>(pr+32);
  f32x16 wr3 = *reinterpret_cast<const f32x16*>(pr+48);
  const float* pi = wih + (size_t)grow*768 + w*96;
  f32x16 wi0 = *reinterpret_cast<const f32x16*>(pi);
  f32x16 wi1 = *reinterpret_cast<const f32x16*>(pi+16);
  f32x16 wi2 = *reinterpret_cast<const f32x16*>(pi+32);
  f32x16 wi3 = *reinterpret_cast<const f32x16*>(pi+48);
  f32x16 wi4 = *reinterpret_cast<const f32x16*>(pi+64);
  f32x16 wi5 = *reinterpret_cast<const f32x16*>(pi+80);

  const float bias = (d?bihb:bihf)[grow] + (d?bhhb:bhhf)[grow];
  const float* h0 = d ? h0b : h0f;
  float hv = h0[w*64 + l];
  float c  = (d?c0b:c0f)[k*16 + (l>>2)];

  __shared__ float part[2][8][64];

#define EPART(X0,X1,B0,B1_,B2_,B3_) \
  DOT16(X0, 0, wi0, B0,B1_,B2_,B3_) DOT16(X0,16, wi1, B0,B1_,B2_,B3_) \
  DOT16(X0,32, wi2, B0,B1_,B2_,B3_) DOT16(X0,48, wi3, B0,B1_,B2_,B3_) \
  DOT16(X1, 0, wi4, B0,B1_,B2_,B3_) DOT16(X1,16, wi5, B0,B1_,B2_,B3_)

  float acc_e;
  {
    const int tA = d ? 8191 : 0;
    const float* e = emb + (size_t)tA*768 + w*96 + l;
    float x0 = e[0];
    float x1 = (l<32) ? e[64] : 0.f;
    float b0=0.f,b1=0.f,b2=0.f,b3=0.f;
    EPART(x0,x1,b0,b1,b2,b3);
    acc_e = (b0+b1)+(b2+b3);
  }
  float ev0, ev1;
  {
    const int tB = d ? 8190 : 1;
    const float* e = emb + (size_t)tB*768 + w*96 + l;
    ev0 = e[0];
    ev1 = (l<32) ? e[64] : 0.f;
  }

  for (int s=0; s<8192; s++){
    const int t  = d ? (8191-s) : s;
    const int pb = s & 1;
    float a0=acc_e, a1=0.f, a2=0.f, a3=0.f;
    DOT16(hv, 0, wr0, a0,a1,a2,a3)
    DOT16(hv,16, wr1, a0,a1,a2,a3)
    DOT16(hv,32, wr2, a0,a1,a2,a3)
    DOT16(hv,48, wr3, a0,a1,a2,a3)
    part[pb][w][l] = (a0+a1)+(a2+a3);
    __syncthreads();

    if (w==0){
      float r = ((part[pb][0][l]+part[pb][1][l])+(part[pb][2][l]+part[pb][3][l]))
              + ((part[pb][4][l]+part[pb][5][l])+(part[pb][6][l]+part[pb][7][l])) + bias;
      const bool isg = ((l&3)==2);
      float xx = isg ? 2.f*r : r;
      float sg = 1.f/(1.f + expf(-xx));
      float a  = isg ? fmaf(2.f,sg,-1.f) : sg;
      const int lb = l & ~3;
      float ig = __shfl(a, lb);
      float fg = __shfl(a, lb+1);
      float gg = __shfl(a, lb+2);
      float og = __shfl(a, lb+3);
      if ((l&3)==0){
        c = fmaf(fg, c, ig*gg);
        float h = og * tanhf(c);
        const int unit = k*16 + (l>>2);
        u64 pk = ((u64)(unsigned)(s+1) << 32) | (u64)__float_as_uint(h);
        __hip_atomic_store(hbuf + (pb<<10) + d*512 + unit, pk,
                           __ATOMIC_RELAXED, __HIP_MEMORY_SCOPE_AGENT);
        H[(size_t)t*1024 + d*512 + unit] = h;
      }
    }

    if (s<8191){
      float nx0=0.f, nx1=0.f;
      if (s<8190){
        const int t2 = d ? (8189-s) : (s+2);
        const float* e = emb + (size_t)t2*768 + w*96 + l;
        nx0 = e[0];
        nx1 = (l<32) ? e[64] : 0.f;
      }
      float b0=0.f,b1=0.f,b2=0.f,b3=0.f;
      EPART(ev0,ev1,b0,b1,b2,b3);
      acc_e = (b0+b1)+(b2+b3);
      ev0=nx0; ev1=nx1;

      const u64* hp = hbuf + (pb<<10) + d*512 + w*64 + l;
      const unsigned want = (unsigned)(s+1);
      u64 p0 = __hip_atomic_load(hp, __ATOMIC_RELAXED, __HIP_MEMORY_SCOPE_AGENT);
      while ((unsigned)(p0>>32) < want){
        __builtin_amdgcn_s_sleep(1);
        p0 = __hip_atomic_load(hp, __ATOMIC_RELAXED, __HIP_MEMORY_SCOPE_AGENT);
      }
      hv = __uint_as_float((unsigned)p0);
    }
  }
#undef EPART
}

// =====================================================================
// K3: feats[t][n] = H[t][:] . w_tag[n][:] + b_tag[n]
// =====================================================================
__global__ void feats_k(const float* __restrict__ H, const float* __restrict__ wtag,
                        const float* __restrict__ btag, float* __restrict__ feats)
{
  const int r = blockIdx.x*4 + (threadIdx.x>>6);
  const int l = threadIdx.x & 63;
  const float* hrow = H + (size_t)r*1024;
  float hv[16];
  #pragma unroll
  for (int j=0;j<16;j++) hv[j] = hrow[j*64 + l];
  #pragma unroll
  for (int n=0;n<5;n++){
    const float* wrow = wtag + n*1024;
    float acc = 0.f;
    #pragma unroll
    for (int j=0;j<16;j++) acc = fmaf(hv[j], wrow[j*64+l], acc);
    #pragma unroll
    for (int off=32; off; off>>=1) acc += __shfl_xor(acc, off);
    if (l==0) feats[r*5+n] = acc + btag[n];
  }
}

// =====================================================================
// V: sequential Viterbi forward. Round-11: the 5 uniform-index __shfl
// broadcasts (ds_bpermute ~40cy) replaced with v_readlane (~10cy) —
// bit-identical values, shorter serial chain.
// =====================================================================
__global__ void vit_fv(const float* __restrict__ feats, const float* __restrict__ trans,
                       int* __restrict__ bps, float* __restrict__ out, int* __restrict__ ebest)
{
  const int l = threadIdx.x & 63;
  const bool active = (l < 25);
  const int n = l/5;
  float tr0=0,tr1=0,tr2=0,tr3=0,tr4=0;
  if (active){ tr0=trans[n*5+0]; tr1=trans[n*5+1]; tr2=trans[n*5+2]; tr3=trans[n*5+3]; tr4=trans[n*5+4]; }
  const float NEG = -10000.0f;
  float fv0=NEG, fv1=NEG, fv2=NEG, fv3=0.f, fv4=NEG;   // START=3

  float ring[16];
  #pragma unroll
  for (int j=0;j<16;j++) ring[j] = active ? feats[j*5+n] : 0.f;

  for (int tb=0; tb<8192; tb+=16){
    #pragma unroll
    for (int j=0;j<16;j++){
      const int t = tb + j;
      float ft = ring[j];
      float m = fv0 + tr0; int a = 0; float v;
      v = fv1 + tr1; if (v > m){ m=v; a=1; }
      v = fv2 + tr2; if (v > m){ m=v; a=2; }
      v = fv3 + tr3; if (v > m){ m=v; a=3; }
      v = fv4 + tr4; if (v > m){ m=v; a=4; }
      float fnew = m + ft;
      if (active && (l%5)==0) bps[t*5+n] = a;
      fv0 = rl(fnew, 0);  fv1 = rl(fnew, 5);  fv2 = rl(fnew, 10);
      fv3 = rl(fnew, 15); fv4 = rl(fnew, 20);
      const int tf = t + 16;
      ring[j] = (active && tf < 8192) ? feats[tf*5+n] : 0.f;
    }
  }
  if (l==0){
    float t0=trans[20], t1=trans[21], t2=trans[22], t3=trans[23], t4=trans[24];
    float m = fv0 + t0; int a = 0; float v;
    v = fv1 + t1; if (v > m){ m=v; a=1; }
    v = fv2 + t2; if (v > m){ m=v; a=2; }
    v = fv3 + t3; if (v > m){ m=v; a=3; }
    v = fv4 + t4; if (v > m){ m=v; a=4; }
    out[0] = m;
    ebest[0] = a;
  }
}

// =====================================================================
// Backtrack: exact integer parallel scan over 256 chunks of 32 steps.
// =====================================================================
__global__ void bt_maps(const int* __restrict__ bps, int* __restrict__ Fc)
{
  __shared__ int sm[160];
  const int c = blockIdx.x, tid = threadIdx.x;
  for (int idx=tid; idx<160; idx+=64) sm[idx] = bps[c*160+idx];
  __syncthreads();
  if (tid<5){
    int cur = tid;
    for (int j=31;j>=0;j--) cur = sm[j*5+cur];
    Fc[c*5+tid] = cur;
  }
}

__global__ void bt_seq(const int* __restrict__ Fc, const int* __restrict__ ebest,
                       int* __restrict__ echunk)
{
  __shared__ int sm[1280];
  const int tid = threadIdx.x;
  for (int idx=tid; idx<1280; idx+=64) sm[idx]=Fc[idx];
  __syncthreads();
  if (tid==0){
    int e = ebest[0];
    for (int c=255;c>=0;c--){ echunk[c]=e; e = sm[c*5+e]; }
  }
}

__global__ void bt_emit(const int* __restrict__ bps, const int* __restrict__ echunk,
                        float* __restrict__ out)
{
  __shared__ int sm[160];
  const int c=blockIdx.x, tid=threadIdx.x;
  for (int idx=tid; idx<160; idx+=64) sm[idx]=bps[c*160+idx];
  __syncthreads();
  if (tid==0){
    int tag = echunk[c];
    out[1 + c*32 + 31] = (float)tag;
    for (int j=31;j>=1;j--){ tag = sm[j*5+tag]; out[1 + c*32 + j-1] = (float)tag; }
  }
}

// =====================================================================
extern "C" void kernel_launch(void* const* d_in, const int* in_sizes, int n_in,
                              void* d_out, int out_size, void* d_ws, size_t ws_size,
                              hipStream_t stream)
{
  (void)in_sizes; (void)n_in; (void)out_size;
  const float* emb  = (const float*)d_in[0];
  const float* wihf = (const float*)d_in[1];
  const float* whhf = (const float*)d_in[2];
  const float* bihf = (const float*)d_in[3];
  const float* bhhf = (const float*)d_in[4];
  const float* wihb = (const float*)d_in[5];
  const float* whhb = (const float*)d_in[6];
  const float* bihb = (const float*)d_in[7];
  const float* bhhb = (const float*)d_in[8];
  const float* wtag = (const float*)d_in[9];
  const float* btag = (const float*)d_in[10];
  const float* h0f  = (const float*)d_in[11];
  const float* c0f  = (const float*)d_in[12];
  const float* h0b  = (const float*)d_in[13];
  const float* c0b  = (const float*)d_in[14];
  const float* trans= (const float*)d_in[15];
  float* out = (float*)d_out;

  char* ws = (char*)d_ws;
  float* H      = (float*)(ws + OFF_H);
  float* feats  = (float*)(ws + OFF_FEATS);
  int*   bps    = (int*)  (ws + OFF_BPS);
  int*   Fc     = (int*)  (ws + OFF_FC);
  int*   echunk = (int*)  (ws + OFF_ECH);
  int*   ebest  = (int*)  (ws + OFF_EBEST);
  int*   rowcnt = (int*)  (ws + OFF_RC);
  u64*   hbuf   = (u64*)  (ws + OFF_HBUF);
  float* xg     = (float*)(ws + OFF_XG);

  // reset row flags + (tag,h) pairs every launch (graph-replay safe)
  hipMemsetAsync(rowcnt, 0, 256 + 16384, stream);

  const bool use_xg = ws_size >= OFF_XG + XG_BYTES;
  if (use_xg){
    fused_k<<<256, 512, 0, stream>>>(emb, wihf, wihb, whhf, whhb,
                                     bihf, bhhf, bihb, bhhb,
                                     h0f, c0f, h0b, c0b, xg, H, hbuf, rowcnt);
  } else {
    lstm_legacy<<<64, 512, 0, stream>>>(emb, whhf, whhb, wihf, wihb,
                                        bihf, bhhf, bihb, bhhb,
                                        h0f, c0f, h0b, c0b, H, hbuf);
  }
  feats_k<<<2048, 256, 0, stream>>>(H, wtag, btag, feats);
  vit_fv<<<1, 64, 0, stream>>>(feats, trans, bps, out, ebest);
  bt_maps<<<256, 64, 0, stream>>>(bps, Fc);
  bt_seq<<<1, 64, 0, stream>>>(Fc, ebest, echunk);
  bt_emit<<<256, 64, 0, stream>>>(bps, echunk, out);
}

// Round 12
// 13459.300 us; speedup vs baseline: 1.1436x; 1.1436x over previous
//
#include <hip/hip_runtime.h>
#include <hip/hip_bf16.h>
#include <math.h>

#define DEV static __device__ __forceinline__

DEV float rl(float v, int i){ return __uint_as_float(__builtin_amdgcn_readlane(__float_as_uint(v), i)); }

typedef float f32x16 __attribute__((ext_vector_type(16)));
typedef unsigned long long u64;

// ---- workspace layout (bytes) ----
static constexpr size_t OFF_H     = 0;                    // 8192*1024*4 = 33554432
static constexpr size_t OFF_FEATS = 33554432;             // 8192*5*4    = 163840
static constexpr size_t OFF_BPS   = OFF_FEATS + 163840;   // 8192*5*4 int
static constexpr size_t OFF_FC    = OFF_BPS + 163840;     // 256*5*4
static constexpr size_t OFF_ECH   = OFF_FC + 5120;        // 256*4
static constexpr size_t OFF_EBEST = OFF_ECH + 1024;       // 256
static constexpr size_t OFF_RC    = OFF_EBEST + 256;      // 64 ints (xg row flags), pad 256
static constexpr size_t OFF_HBUF  = OFF_RC + 256;         // 2*1024*8 = 16384
static constexpr size_t OFF_XG    = OFF_HBUF + 16384;     // 2*8192*2048*4
static constexpr size_t XG_BYTES  = 2ull*8192*2048*4;

#define DOT16(X, OFF, W, B0, B1_, B2_, B3_) \
  _Pragma("unroll") for (int i=0;i<16;i+=4){ \
    B0 =fmaf(rl(X,OFF+i+0),W[i+0],B0 ); B1_=fmaf(rl(X,OFF+i+1),W[i+1],B1_); \
    B2_=fmaf(rl(X,OFF+i+2),W[i+2],B2_); B3_=fmaf(rl(X,OFF+i+3),W[i+3],B3_); }

// =====================================================================
// xg tile worker: one 128x128 fp32 GEMM tile of xg[d][t][row] =
// emb . wih^T. Agent-scope u64 stores (write-through to MALL — per-XCD
// L2s aren't cross-coherent; write-back stores would strand dirty lines).
// Joint __syncthreads drains vmcnt(0) before the row-flag bump.
// =====================================================================
DEV void xg_tile(const float* __restrict__ emb, const float* __restrict__ wihf,
                 const float* __restrict__ wihb, float* __restrict__ xg,
                 int* rowcnt, int tm32, int tn32, bool doflag,
                 float (*As)[132], float (*Bs)[132], int tid)
{
  const int tmb = tm32*128, tnb = tn32*128;
  const int ty = tid >> 4, tx = tid & 15;
  float acc[8][8];
  #pragma unroll
  for (int i=0;i<8;i++)
    #pragma unroll
    for (int j=0;j<8;j++) acc[i][j] = 0.f;

  const int m  = tid & 127;
  const int n  = tnb + m;
  const float* wih = (n & 2048) ? wihb : wihf;
  const float* arow = emb + (size_t)(tmb+m)*768;
  const float* brow = wih + (size_t)(n&2047)*768;
  const int kq = (tid >> 7) << 2;

  for (int k0=0; k0<768; k0+=16){
    #pragma unroll
    for (int r=0;r<2;r++){
      const int kk = kq + r*8;
      float4 v = *reinterpret_cast<const float4*>(arow + k0 + kk);
      As[kk+0][m]=v.x; As[kk+1][m]=v.y; As[kk+2][m]=v.z; As[kk+3][m]=v.w;
      float4 u = *reinterpret_cast<const float4*>(brow + k0 + kk);
      Bs[kk+0][m]=u.x; Bs[kk+1][m]=u.y; Bs[kk+2][m]=u.z; Bs[kk+3][m]=u.w;
    }
    __syncthreads();   // joint 512-thread barrier (both sub-blocks aligned)
    #pragma unroll
    for (int kk2=0;kk2<16;kk2++){
      float4 a0 = *reinterpret_cast<const float4*>(&As[kk2][ty*8]);
      float4 a1 = *reinterpret_cast<const float4*>(&As[kk2][ty*8+4]);
      float4 b0 = *reinterpret_cast<const float4*>(&Bs[kk2][tx*8]);
      float4 b1 = *reinterpret_cast<const float4*>(&Bs[kk2][tx*8+4]);
      float af[8] = {a0.x,a0.y,a0.z,a0.w,a1.x,a1.y,a1.z,a1.w};
      float bf[8] = {b0.x,b0.y,b0.z,b0.w,b1.x,b1.y,b1.z,b1.w};
      #pragma unroll
      for (int i=0;i<8;i++)
        #pragma unroll
        for (int j=0;j<8;j++) acc[i][j] = fmaf(af[i], bf[j], acc[i][j]);
    }
    __syncthreads();
  }

  const int dd = tnb >> 11, nb = tnb & 2047;
  float* xgp = xg + (size_t)dd*8192*2048;
  #pragma unroll
  for (int i=0;i<8;i++){
    float* orow = xgp + (size_t)(tmb+ty*8+i)*2048 + nb + tx*8;
    #pragma unroll
    for (int j=0;j<8;j+=2){
      u64 uu = ((u64)__float_as_uint(acc[i][j+1])<<32) | (u64)__float_as_uint(acc[i][j]);
      __hip_atomic_store(reinterpret_cast<u64*>(orow + j), uu,
                         __ATOMIC_RELAXED, __HIP_MEMORY_SCOPE_AGENT);
    }
  }
  __syncthreads();   // implies s_waitcnt vmcnt(0): agent stores acked at MALL
  if (doflag && tid==0)
    __hip_atomic_fetch_add(rowcnt + tm32, 1, __ATOMIC_RELAXED, __HIP_MEMORY_SCOPE_AGENT);
}

DEV void wait_row(const int* rc, int tm){
  while (__hip_atomic_load(rc + tm, __ATOMIC_RELAXED, __HIP_MEMORY_SCOPE_AGENT) < 32)
    __builtin_amdgcn_s_sleep(8);
  __builtin_amdgcn_sched_barrier(0);
  asm volatile("" ::: "memory");
}

// =====================================================================
// fused_k: 256 blocks x 512 threads (1 block/CU, all co-resident).
//  - blocks 0..63: round-5 persistent BiLSTM with the ROUND-10 poll
//    (single dependent agent load, sleep after 4 spins — proven
//    12.59ms). Round-11's 4-deep pipelined poll REVERTED: same-address
//    loads serialize at the MALL, and detection shifted through a
//    3-deep queue — +250ns/step measured.
//  - blocks 64..255: 384 xg-GEMM workers, both-ends-first tile order.
// Step floor (7 experiments): ~0.4us compute + ~1.1us MALL rendezvous.
// =====================================================================
__global__ __launch_bounds__(512,2) void fused_k(
    const float* __restrict__ emb,
    const float* __restrict__ wihf, const float* __restrict__ wihb,
    const float* __restrict__ whhf, const float* __restrict__ whhb,
    const float* __restrict__ bihf, const float* __restrict__ bhhf,
    const float* __restrict__ bihb, const float* __restrict__ bhhb,
    const float* __restrict__ h0f, const float* __restrict__ c0f,
    const float* __restrict__ h0b, const float* __restrict__ c0b,
    float* __restrict__ xg, float* __restrict__ H,
    u64* __restrict__ hbuf, int* __restrict__ rowcnt)
{
  __shared__ float smemf[8448];   // workers: 2 x (As+Bs); lstm: part[2][8][64]
  const int b = blockIdx.x;

  if (b >= 64){
    // ---------------- xg worker ----------------
    const int tid = threadIdx.x & 255;
    const int sb  = threadIdx.x >> 8;
    float (*As)[132] = (float(*)[132])(smemf + sb*4224);
    float (*Bs)[132] = (float(*)[132])(smemf + sb*4224 + 2112);
    const int wkr = (b - 64)*2 + sb;          // 0..383
    for (int r=0; r<6; r++){                  // fixed trip for barrier alignment
      int j = wkr + r*384;
      const bool real = (j < 2048);
      if (!real) j = 2047;                    // dummy recompute (flag skipped)
      const int p = j >> 5, tn32 = j & 31;
      const int tm32 = (p & 1) ? (63 - (p>>1)) : (p>>1);   // 0,63,1,62,...
      xg_tile(emb, wihf, wihb, xg, rowcnt, tm32, tn32, real, As, Bs, tid);
    }
    return;
  }

  // ---------------- LSTM role (round-5 body) ----------------
  float (*part)[8][64] = (float(*)[8][64])smemf;   // [2][8][64]
  const int d  = b >> 5;
  const int k  = b & 31;
  const int tid = threadIdx.x;
  const int w  = tid >> 6;
  const int l  = tid & 63;

  const float* whh = d ? whhb : whhf;
  const int grow = (l&3)*512 + k*16 + (l>>2);

  const float* pr = whh + (size_t)grow*512 + w*64;
  f32x16 wr0 = *reinterpret_cast<const f32x16*>(pr);
  f32x16 wr1 = *reinterpret_cast<const f32x16*>(pr+16);
  f32x16 wr2 = *reinterpret_cast<const f32x16*>(pr+32);
  f32x16 wr3 = *reinterpret_cast<const f32x16*>(pr+48);

  const float bias = (d?bihb:bihf)[grow] + (d?bhhb:bhhf)[grow];
  const float* xgp = xg + (size_t)d*8192*2048;

  const float* h0 = d ? h0b : h0f;
  float hv = h0[w*64 + l];
  float c  = (d?c0b:c0f)[k*16 + (l>>2)];

  float xq0 = 0.f, xq1 = 0.f;
  if (w==0){
    wait_row(rowcnt, d ? 63 : 0);           // gate the prologue tile
    xq0 = xgp[(size_t)(d?8191:0)*2048 + grow];
    xq1 = xgp[(size_t)(d?8190:1)*2048 + grow];
  }

  for (int s=0; s<8192; s++){
    const int t  = d ? (8191-s) : s;
    const int pb = s & 1;
    float a0=0.f, a1=0.f, a2=0.f, a3=0.f;
    DOT16(hv, 0, wr0, a0,a1,a2,a3)
    DOT16(hv,16, wr1, a0,a1,a2,a3)
    DOT16(hv,32, wr2, a0,a1,a2,a3)
    DOT16(hv,48, wr3, a0,a1,a2,a3)
    part[pb][w][l] = (a0+a1)+(a2+a3);
    __syncthreads();

    if (w==0){
      float r = ((part[pb][0][l]+part[pb][1][l])+(part[pb][2][l]+part[pb][3][l]))
              + ((part[pb][4][l]+part[pb][5][l])+(part[pb][6][l]+part[pb][7][l]))
              + bias + xq0;
      const bool isg = ((l&3)==2);
      float xx = isg ? 2.f*r : r;
      float sg = 1.f/(1.f + expf(-xx));        // sigmoid
      float a  = isg ? fmaf(2.f,sg,-1.f) : sg; // tanh via 2*sig(2x)-1 for g-gate
      const int lb = l & ~3;
      float ig = __shfl(a, lb);
      float fg = __shfl(a, lb+1);
      float gg = __shfl(a, lb+2);
      float og = __shfl(a, lb+3);
      if ((l&3)==0){
        c = fmaf(fg, c, ig*gg);
        float h = og * tanhf(c);
        const int unit = k*16 + (l>>2);
        u64 pk = ((u64)(unsigned)(s+1) << 32) | (u64)__float_as_uint(h);
        __hip_atomic_store(hbuf + (pb<<10) + d*512 + unit, pk,
                           __ATOMIC_RELAXED, __HIP_MEMORY_SCOPE_AGENT);
        H[(size_t)t*1024 + d*512 + unit] = h;
      }
      // depth-2 xg prefetch for t(s+2), gated at 128-row tile boundaries
      xq0 = xq1;
      if (s<8190){
        const int t2 = d ? (8189-s) : (s+2);
        if (d==0 ? ((t2 & 127)==0) : ((t2 & 127)==127)) wait_row(rowcnt, t2>>7);
        xq1 = xgp[(size_t)t2*2048 + grow];
      }
    }

    if (s<8191){
      const u64* hp = hbuf + (pb<<10) + d*512 + w*64 + l;
      const unsigned want = (unsigned)(s+1);
      u64 p0 = __hip_atomic_load(hp, __ATOMIC_RELAXED, __HIP_MEMORY_SCOPE_AGENT);
      int it = 0;
      while ((unsigned)(p0>>32) < want){
        if (++it > 4) __builtin_amdgcn_s_sleep(1);   // tight first spins
        p0 = __hip_atomic_load(hp, __ATOMIC_RELAXED, __HIP_MEMORY_SCOPE_AGENT);
      }
      hv = __uint_as_float((unsigned)p0);
    }
  }
}

// =====================================================================
// Legacy fallback (round-4/5 single-kernel path) — only if ws too small.
// =====================================================================
__global__ __launch_bounds__(512,2) void lstm_legacy(
    const float* __restrict__ emb,
    const float* __restrict__ whhf, const float* __restrict__ whhb,
    const float* __restrict__ wihf, const float* __restrict__ wihb,
    const float* __restrict__ bihf, const float* __restrict__ bhhf,
    const float* __restrict__ bihb, const float* __restrict__ bhhb,
    const float* __restrict__ h0f, const float* __restrict__ c0f,
    const float* __restrict__ h0b, const float* __restrict__ c0b,
    float* __restrict__ H, u64* __restrict__ hbuf)
{
  const int b  = blockIdx.x;
  const int d  = b >> 5;
  const int k  = b & 31;
  const int tid = threadIdx.x;
  const int w  = tid >> 6;
  const int l  = tid & 63;

  const float* whh = d ? whhb : whhf;
  const float* wih = d ? wihb : wihf;
  const int grow = (l&3)*512 + k*16 + (l>>2);

  const float* pr = whh + (size_t)grow*512 + w*64;
  f32x16 wr0 = *reinterpret_cast<const f32x16*>(pr);
  f32x16 wr1 = *reinterpret_cast<const f32x16*>(pr+16);
  f32x16 wr2 = *reinterpret_cast<const f32x16*>(pr+32);
  f32x16 wr3 = *reinterpret_cast<const f32x16*>(pr+48);
  const float* pi = wih + (size_t)grow*768 + w*96;
  f32x16 wi0 = *reinterpret_cast<const f32x16*>(pi);
  f32x16 wi1 = *reinterpret_cast<const f32x16*>(pi+16);
  f32x16 wi2 = *reinterpret_cast<const f32x16*>(pi+32);
  f32x16 wi3 = *reinterpret_cast<const f32x16*>(pi+48);
  f32x16 wi4 = *reinterpret_cast<const f32x16*>(pi+64);
  f32x16 wi5 = *reinterpret_cast<const f32x16*>(pi+80);

  const float bias = (d?bihb:bihf)[grow] + (d?bhhb:bhhf)[grow];
  const float* h0 = d ? h0b : h0f;
  float hv = h0[w*64 + l];
  float c  = (d?c0b:c0f)[k*16 + (l>>2)];

  __shared__ float part[2][8][64];

#define EPART(X0,X1,B0,B1_,B2_,B3_) \
  DOT16(X0, 0, wi0, B0,B1_,B2_,B3_) DOT16(X0,16, wi1, B0,B1_,B2_,B3_) \
  DOT16(X0,32, wi2, B0,B1_,B2_,B3_) DOT16(X0,48, wi3, B0,B1_,B2_,B3_) \
  DOT16(X1, 0, wi4, B0,B1_,B2_,B3_) DOT16(X1,16, wi5, B0,B1_,B2_,B3_)

  float acc_e;
  {
    const int tA = d ? 8191 : 0;
    const float* e = emb + (size_t)tA*768 + w*96 + l;
    float x0 = e[0];
    float x1 = (l<32) ? e[64] : 0.f;
    float b0=0.f,b1=0.f,b2=0.f,b3=0.f;
    EPART(x0,x1,b0,b1,b2,b3);
    acc_e = (b0+b1)+(b2+b3);
  }
  float ev0, ev1;
  {
    const int tB = d ? 8190 : 1;
    const float* e = emb + (size_t)tB*768 + w*96 + l;
    ev0 = e[0];
    ev1 = (l<32) ? e[64] : 0.f;
  }

  for (int s=0; s<8192; s++){
    const int t  = d ? (8191-s) : s;
    const int pb = s & 1;
    float a0=acc_e, a1=0.f, a2=0.f, a3=0.f;
    DOT16(hv, 0, wr0, a0,a1,a2,a3)
    DOT16(hv,16, wr1, a0,a1,a2,a3)
    DOT16(hv,32, wr2, a0,a1,a2,a3)
    DOT16(hv,48, wr3, a0,a1,a2,a3)
    part[pb][w][l] = (a0+a1)+(a2+a3);
    __syncthreads();

    if (w==0){
      float r = ((part[pb][0][l]+part[pb][1][l])+(part[pb][2][l]+part[pb][3][l]))
              + ((part[pb][4][l]+part[pb][5][l])+(part[pb][6][l]+part[pb][7][l])) + bias;
      const bool isg = ((l&3)==2);
      float xx = isg ? 2.f*r : r;
      float sg = 1.f/(1.f + expf(-xx));
      float a  = isg ? fmaf(2.f,sg,-1.f) : sg;
      const int lb = l & ~3;
      float ig = __shfl(a, lb);
      float fg = __shfl(a, lb+1);
      float gg = __shfl(a, lb+2);
      float og = __shfl(a, lb+3);
      if ((l&3)==0){
        c = fmaf(fg, c, ig*gg);
        float h = og * tanhf(c);
        const int unit = k*16 + (l>>2);
        u64 pk = ((u64)(unsigned)(s+1) << 32) | (u64)__float_as_uint(h);
        __hip_atomic_store(hbuf + (pb<<10) + d*512 + unit, pk,
                           __ATOMIC_RELAXED, __HIP_MEMORY_SCOPE_AGENT);
        H[(size_t)t*1024 + d*512 + unit] = h;
      }
    }

    if (s<8191){
      float nx0=0.f, nx1=0.f;
      if (s<8190){
        const int t2 = d ? (8189-s) : (s+2);
        const float* e = emb + (size_t)t2*768 + w*96 + l;
        nx0 = e[0];
        nx1 = (l<32) ? e[64] : 0.f;
      }
      float b0=0.f,b1=0.f,b2=0.f,b3=0.f;
      EPART(ev0,ev1,b0,b1,b2,b3);
      acc_e = (b0+b1)+(b2+b3);
      ev0=nx0; ev1=nx1;

      const u64* hp = hbuf + (pb<<10) + d*512 + w*64 + l;
      const unsigned want = (unsigned)(s+1);
      u64 p0 = __hip_atomic_load(hp, __ATOMIC_RELAXED, __HIP_MEMORY_SCOPE_AGENT);
      while ((unsigned)(p0>>32) < want){
        __builtin_amdgcn_s_sleep(1);
        p0 = __hip_atomic_load(hp, __ATOMIC_RELAXED, __HIP_MEMORY_SCOPE_AGENT);
      }
      hv = __uint_as_float((unsigned)p0);
    }
  }
#undef EPART
}

// =====================================================================
// K3: feats[t][n] = H[t][:] . w_tag[n][:] + b_tag[n]
// =====================================================================
__global__ void feats_k(const float* __restrict__ H, const float* __restrict__ wtag,
                        const float* __restrict__ btag, float* __restrict__ feats)
{
  const int r = blockIdx.x*4 + (threadIdx.x>>6);
  const int l = threadIdx.x & 63;
  const float* hrow = H + (size_t)r*1024;
  float hv[16];
  #pragma unroll
  for (int j=0;j<16;j++) hv[j] = hrow[j*64 + l];
  #pragma unroll
  for (int n=0;n<5;n++){
    const float* wrow = wtag + n*1024;
    float acc = 0.f;
    #pragma unroll
    for (int j=0;j<16;j++) acc = fmaf(hv[j], wrow[j*64+l], acc);
    #pragma unroll
    for (int off=32; off; off>>=1) acc += __shfl_xor(acc, off);
    if (l==0) feats[r*5+n] = acc + btag[n];
  }
}

// =====================================================================
// V: sequential Viterbi forward (exact fp32, reference association
// order); uniform-index broadcasts via v_readlane (bit-identical).
// =====================================================================
__global__ void vit_fv(const float* __restrict__ feats, const float* __restrict__ trans,
                       int* __restrict__ bps, float* __restrict__ out, int* __restrict__ ebest)
{
  const int l = threadIdx.x & 63;
  const bool active = (l < 25);
  const int n = l/5;
  float tr0=0,tr1=0,tr2=0,tr3=0,tr4=0;
  if (active){ tr0=trans[n*5+0]; tr1=trans[n*5+1]; tr2=trans[n*5+2]; tr3=trans[n*5+3]; tr4=trans[n*5+4]; }
  const float NEG = -10000.0f;
  float fv0=NEG, fv1=NEG, fv2=NEG, fv3=0.f, fv4=NEG;   // START=3

  float ring[16];
  #pragma unroll
  for (int j=0;j<16;j++) ring[j] = active ? feats[j*5+n] : 0.f;

  for (int tb=0; tb<8192; tb+=16){
    #pragma unroll
    for (int j=0;j<16;j++){
      const int t = tb + j;
      float ft = ring[j];
      float m = fv0 + tr0; int a = 0; float v;
      v = fv1 + tr1; if (v > m){ m=v; a=1; }
      v = fv2 + tr2; if (v > m){ m=v; a=2; }
      v = fv3 + tr3; if (v > m){ m=v; a=3; }
      v = fv4 + tr4; if (v > m){ m=v; a=4; }
      float fnew = m + ft;
      if (active && (l%5)==0) bps[t*5+n] = a;
      fv0 = rl(fnew, 0);  fv1 = rl(fnew, 5);  fv2 = rl(fnew, 10);
      fv3 = rl(fnew, 15); fv4 = rl(fnew, 20);
      const int tf = t + 16;
      ring[j] = (active && tf < 8192) ? feats[tf*5+n] : 0.f;
    }
  }
  if (l==0){
    float t0=trans[20], t1=trans[21], t2=trans[22], t3=trans[23], t4=trans[24];
    float m = fv0 + t0; int a = 0; float v;
    v = fv1 + t1; if (v > m){ m=v; a=1; }
    v = fv2 + t2; if (v > m){ m=v; a=2; }
    v = fv3 + t3; if (v > m){ m=v; a=3; }
    v = fv4 + t4; if (v > m){ m=v; a=4; }
    out[0] = m;
    ebest[0] = a;
  }
}

// =====================================================================
// Backtrack: exact integer parallel scan over 256 chunks of 32 steps.
// =====================================================================
__global__ void bt_maps(const int* __restrict__ bps, int* __restrict__ Fc)
{
  __shared__ int sm[160];
  const int c = blockIdx.x, tid = threadIdx.x;
  for (int idx=tid; idx<160; idx+=64) sm[idx] = bps[c*160+idx];
  __syncthreads();
  if (tid<5){
    int cur = tid;
    for (int j=31;j>=0;j--) cur = sm[j*5+cur];
    Fc[c*5+tid] = cur;
  }
}

__global__ void bt_seq(const int* __restrict__ Fc, const int* __restrict__ ebest,
                       int* __restrict__ echunk)
{
  __shared__ int sm[1280];
  const int tid = threadIdx.x;
  for (int idx=tid; idx<1280; idx+=64) sm[idx]=Fc[idx];
  __syncthreads();
  if (tid==0){
    int e = ebest[0];
    for (int c=255;c>=0;c--){ echunk[c]=e; e = sm[c*5+e]; }
  }
}

__global__ void bt_emit(const int* __restrict__ bps, const int* __restrict__ echunk,
                        float* __restrict__ out)
{
  __shared__ int sm[160];
  const int c=blockIdx.x, tid=threadIdx.x;
  for (int idx=tid; idx<160; idx+=64) sm[idx]=bps[c*160+idx];
  __syncthreads();
  if (tid==0){
    int tag = echunk[c];
    out[1 + c*32 + 31] = (float)tag;
    for (int j=31;j>=1;j--){ tag = sm[j*5+tag]; out[1 + c*32 + j-1] = (float)tag; }
  }
}

// =====================================================================
extern "C" void kernel_launch(void* const* d_in, const int* in_sizes, int n_in,
                              void* d_out, int out_size, void* d_ws, size_t ws_size,
                              hipStream_t stream)
{
  (void)in_sizes; (void)n_in; (void)out_size;
  const float* emb  = (const float*)d_in[0];
  const float* wihf = (const float*)d_in[1];
  const float* whhf = (const float*)d_in[2];
  const float* bihf = (const float*)d_in[3];
  const float* bhhf = (const float*)d_in[4];
  const float* wihb = (const float*)d_in[5];
  const float* whhb = (const float*)d_in[6];
  const float* bihb = (const float*)d_in[7];
  const float* bhhb = (const float*)d_in[8];
  const float* wtag = (const float*)d_in[9];
  const float* btag = (const float*)d_in[10];
  const float* h0f  = (const float*)d_in[11];
  const float* c0f  = (const float*)d_in[12];
  const float* h0b  = (const float*)d_in[13];
  const float* c0b  = (const float*)d_in[14];
  const float* trans= (const float*)d_in[15];
  float* out = (float*)d_out;

  char* ws = (char*)d_ws;
  float* H      = (float*)(ws + OFF_H);
  float* feats  = (float*)(ws + OFF_FEATS);
  int*   bps    = (int*)  (ws + OFF_BPS);
  int*   Fc     = (int*)  (ws + OFF_FC);
  int*   echunk = (int*)  (ws + OFF_ECH);
  int*   ebest  = (int*)  (ws + OFF_EBEST);
  int*   rowcnt = (int*)  (ws + OFF_RC);
  u64*   hbuf   = (u64*)  (ws + OFF_HBUF);
  float* xg     = (float*)(ws + OFF_XG);

  // reset row flags + (tag,h) pairs every launch (graph-replay safe)
  hipMemsetAsync(rowcnt, 0, 256 + 16384, stream);

  const bool use_xg = ws_size >= OFF_XG + XG_BYTES;
  if (use_xg){
    fused_k<<<256, 512, 0, stream>>>(emb, wihf, wihb, whhf, whhb,
                                     bihf, bhhf, bihb, bhhb,
                                     h0f, c0f, h0b, c0b, xg, H, hbuf, rowcnt);
  } else {
    lstm_legacy<<<64, 512, 0, stream>>>(emb, whhf, whhb, wihf, wihb,
                                        bihf, bhhf, bihb, bhhb,
                                        h0f, c0f, h0b, c0b, H, hbuf);
  }
  feats_k<<<2048, 256, 0, stream>>>(H, wtag, btag, feats);
  vit_fv<<<1, 64, 0, stream>>>(feats, trans, bps, out, ebest);
  bt_maps<<<256, 64, 0, stream>>>(bps, Fc);
  bt_seq<<<1, 64, 0, stream>>>(Fc, ebest, echunk);
  bt_emit<<<256, 64, 0, stream>>>(bps, echunk, out);
}